// Round 7
// baseline (197.588 us; speedup 1.0000x reference)
//
#include <hip/hip_runtime.h>
#include <float.h>

#define K_CODES 1024
#define DIM 64
#define BR 128
// Distances in the MFMA path are HALF-scale (ne/2 - sim, z pre-negated,
// norms pre-halved). bf16x3 half-scale error bound: 3*2^-18*||z||*||e||
// <= 7e-5 worst-case; gate at 1.25e-4 (== round-5/6's 2.5e-4 full-scale,
// which flagged ~113/65536 rows).
#define SAFE_MARGIN_H 1.25e-4f

typedef __attribute__((ext_vector_type(8))) short bf16x8;
typedef __attribute__((ext_vector_type(8))) unsigned short u16x8;
typedef __attribute__((ext_vector_type(4))) float f32x4;

__device__ __forceinline__ unsigned short f2bf(float f) {
    unsigned int u = __float_as_uint(f);
    u += 0x7fff + ((u >> 16) & 1);          // round-to-nearest-even
    return (unsigned short)(u >> 16);
}
__device__ __forceinline__ float bf2f(unsigned short h) {
    return __uint_as_float(((unsigned int)h) << 16);
}
// XOR swizzle for 128-byte LDS rows, applied on BOTH write & read sides.
__device__ __forceinline__ int swz(int row, int byteInRow) {
    return row * 128 + (byteInRow ^ ((row & 7) << 4));
}

// ---------- prep: transpose E, bf16 hi/lo splits, norms (+halved) ----------
__global__ __launch_bounds__(256) void vq_prep2(
    const float* __restrict__ E, float* __restrict__ Et,
    unsigned short* __restrict__ Eh, unsigned short* __restrict__ El,
    float* __restrict__ nrm, float* __restrict__ nrm2)
{
    __shared__ float T[64 * 17];
    const int t = threadIdx.x;
    const int k0 = blockIdx.x * 16;
    #pragma unroll
    for (int i = 0; i < 4; ++i) {
        int idx = i * 256 + t;
        int d = idx >> 4, kk = idx & 15;
        T[d * 17 + kk] = E[d * K_CODES + k0 + kk];
    }
    __syncthreads();
    #pragma unroll
    for (int i = 0; i < 4; ++i) {
        int idx = i * 256 + t;
        int kk = idx >> 6, d = idx & 63;
        float v = T[d * 17 + kk];
        Et[(size_t)(k0 + kk) * DIM + d] = v;
        unsigned short h = f2bf(v);
        Eh[(size_t)(k0 + kk) * DIM + d] = h;
        El[(size_t)(k0 + kk) * DIM + d] = f2bf(v - bf2f(h));
    }
    if (t < 16) {
        float s = 0.f;
        #pragma unroll
        for (int d = 0; d < DIM; ++d) {
            float v = T[d * 17 + t];
            s = __builtin_fmaf(v, v, s);
        }
        nrm [k0 + t] = s;
        nrm2[k0 + t] = 0.5f * s;    // exact (exponent decrement)
    }
}

// ---------- main: bf16x3 MFMA + med3 top-2 + fused gather + fused refine ----------
// LDS overlay: [0,32K) = A-stage (Ah|Al), then reused per-chunk as B (Bh|Bl),
// then reused by the (rare) refine phase. [32K,...) = bidx / flag list / fcnt.
__global__ __launch_bounds__(256, 4) void vq_mfma(
    const float* __restrict__ x,
    const float* __restrict__ E,
    const unsigned short* __restrict__ Eh,
    const unsigned short* __restrict__ El,
    const float* __restrict__ nrm,
    const float* __restrict__ nrm2,
    const float* __restrict__ Et,
    float* __restrict__ out)
{
    __shared__ char lds[32768 + 512 + 512 + 16];
    char* Ah = lds;                      // 16 KB (stage phase)
    char* Al = lds + 16384;              // 16 KB (stage phase)
    char* Bh = lds;                      // 16 KB (chunk phase)
    char* Bl = lds + 16384;              // 16 KB (chunk phase)
    int*  bidx  = (int*)(lds + 32768);   // 128 winners
    int*  flist = (int*)(lds + 33280);   // flagged local rows (<=128)
    int*  fcnt  = (int*)(lds + 33792);

    const int t    = threadIdx.x;
    const int lane = t & 63;
    const int wv   = t >> 6;
    const int col  = lane & 15;
    const int q    = lane >> 4;
    const int koff = q * 16;
    const long r0  = (long)blockIdx.x * BR;

    if (t == 0) *fcnt = 0;

    // ---- stage A: load x rows, split NEGATED fp32 -> bf16 hi/lo ----
    {
        int row = t >> 1, h = t & 1;
        const float4* src = (const float4*)(x + (r0 + row) * DIM + h * 32);
        float v[32];
        #pragma unroll
        for (int i = 0; i < 8; ++i) {
            float4 f = src[i];
            v[4*i+0] = -f.x; v[4*i+1] = -f.y; v[4*i+2] = -f.z; v[4*i+3] = -f.w;
        }
        unsigned short hi[32], lo[32];
        #pragma unroll
        for (int i = 0; i < 32; ++i) {
            hi[i] = f2bf(v[i]);
            lo[i] = f2bf(v[i] - bf2f(hi[i]));
        }
        #pragma unroll
        for (int s = 0; s < 2; ++s) {
            int seg = h * 2 + s;
            *(u16x8*)(Ah + swz(row, seg*32))      = *(u16x8*)(hi + s*16);
            *(u16x8*)(Ah + swz(row, seg*32 + 16)) = *(u16x8*)(hi + s*16 + 8);
            *(u16x8*)(Al + swz(row, seg*32))      = *(u16x8*)(lo + s*16);
            *(u16x8*)(Al + swz(row, seg*32 + 16)) = *(u16x8*)(lo + s*16 + 8);
        }
    }
    __syncthreads();

    // ---- A fragments (-z) held in VGPRs: A[row=lane&15][k=(lane>>4)*8+j] ----
    bf16x8 aH[2][2], aL[2][2];
    #pragma unroll
    for (int m = 0; m < 2; ++m) {
        int arow = wv * 32 + m * 16 + col;
        #pragma unroll
        for (int kk = 0; kk < 2; ++kk) {
            aH[m][kk] = *(bf16x8*)(Ah + swz(arow, kk*64 + koff));
            aL[m][kk] = *(bf16x8*)(Al + swz(arow, kk*64 + koff));
        }
    }
    __syncthreads();   // frags read; A region may be overwritten by B chunks

    float b1[2][4], b2[2][4];
    int   i1[2][4];
    #pragma unroll
    for (int m = 0; m < 2; ++m)
        #pragma unroll
        for (int j = 0; j < 4; ++j) { b1[m][j] = FLT_MAX; b2[m][j] = FLT_MAX; i1[m][j] = 0x7fffffff; }

    for (int c0 = 0; c0 < K_CODES; c0 += 128) {
        // stage B chunk into the (now free) 32 KB region
        #pragma unroll
        for (int i = 0; i < 4; ++i) {
            int idx = i * 256 + t;
            int cr = idx >> 3, sg = idx & 7;
            *(u16x8*)(Bh + swz(cr, sg*16)) = *(const u16x8*)(Eh + (size_t)(c0+cr)*DIM + sg*8);
            *(u16x8*)(Bl + swz(cr, sg*16)) = *(const u16x8*)(El + (size_t)(c0+cr)*DIM + sg*8);
        }
        __syncthreads();

        #pragma unroll
        for (int nt = 0; nt < 8; ++nt) {
            int brow = nt * 16 + col;
            bf16x8 bH0 = *(bf16x8*)(Bh + swz(brow, koff));
            bf16x8 bH1 = *(bf16x8*)(Bh + swz(brow, 64 + koff));
            bf16x8 bL0 = *(bf16x8*)(Bl + swz(brow, koff));
            bf16x8 bL1 = *(bf16x8*)(Bl + swz(brow, 64 + koff));
            int code = c0 + nt * 16 + col;
            float ne2 = nrm2[code];
            #pragma unroll
            for (int m = 0; m < 2; ++m) {
                f32x4 acc = {ne2, ne2, ne2, ne2};   // C-in carries ne/2; A = -z
                acc = __builtin_amdgcn_mfma_f32_16x16x32_bf16(aH[m][0], bH0, acc, 0,0,0);
                acc = __builtin_amdgcn_mfma_f32_16x16x32_bf16(aH[m][1], bH1, acc, 0,0,0);
                acc = __builtin_amdgcn_mfma_f32_16x16x32_bf16(aH[m][0], bL0, acc, 0,0,0);
                acc = __builtin_amdgcn_mfma_f32_16x16x32_bf16(aH[m][1], bL1, acc, 0,0,0);
                acc = __builtin_amdgcn_mfma_f32_16x16x32_bf16(aL[m][0], bH0, acc, 0,0,0);
                acc = __builtin_amdgcn_mfma_f32_16x16x32_bf16(aL[m][1], bH1, acc, 0,0,0);
                #pragma unroll
                for (int j = 0; j < 4; ++j) {
                    float d = acc[j];               // = ne/2 - sim' directly
                    bool lt = d < b1[m][j];
                    float nb1 = fminf(b1[m][j], d);
                    b2[m][j] = __builtin_amdgcn_fmed3f(b1[m][j], b2[m][j], d);
                    i1[m][j] = lt ? code : i1[m][j];
                    b1[m][j] = nb1;
                }
            }
        }
        __syncthreads();   // compute done; next chunk may overwrite B
    }

    // ---- top-2 merge across the 16 lanes holding each row ----
    #pragma unroll
    for (int msk = 1; msk < 16; msk <<= 1) {
        #pragma unroll
        for (int m = 0; m < 2; ++m)
            #pragma unroll
            for (int j = 0; j < 4; ++j) {
                float o1 = __shfl_xor(b1[m][j], msk, 64);
                int   oi = __shfl_xor(i1[m][j], msk, 64);
                float o2 = __shfl_xor(b2[m][j], msk, 64);
                bool take = (o1 < b1[m][j]) || (o1 == b1[m][j] && oi < i1[m][j]);
                float worst = take ? b1[m][j] : o1;
                if (take) { b1[m][j] = o1; i1[m][j] = oi; }
                b2[m][j] = fminf(fminf(b2[m][j], o2), worst);
            }
    }
    if (col == 0) {
        #pragma unroll
        for (int m = 0; m < 2; ++m)
            #pragma unroll
            for (int j = 0; j < 4; ++j) {
                int rowl = wv * 32 + m * 16 + q * 4 + j;   // C/D: row=(lane>>4)*4+reg
                bidx[rowl] = i1[m][j];
                if (b2[m][j] - b1[m][j] <= SAFE_MARGIN_H) {
                    int p = atomicAdd(fcnt, 1);            // LDS atomic
                    flist[p] = rowl;
                }
            }
    }
    __syncthreads();

    // ---- fused gather: bit-exact embedding rows ----
    {
        int rowl = t >> 1, h = t & 1;
        int code = bidx[rowl];
        const float4* src = (const float4*)(Et + (size_t)code * DIM + h * 32);
        float4* dst = (float4*)(out + (size_t)(r0 + rowl) * DIM + h * 32);
        #pragma unroll
        for (int i = 0; i < 8; ++i) dst[i] = src[i];
    }
    __syncthreads();

    // ---- fused refine: exact fp32 re-solve for flagged rows (rare) ----
    // Proven arithmetic: sequential-d fmaf chains, fmaf(-2, acc, zn + nrm).
    // 4 codes/thread (t, t+256, t+512, t+768), coalesced native-E reads.
    const int nf = *fcnt;
    if (nf > 0) {
        float* zsh    = (float*)lds;            // B region is free now
        float* rv     = (float*)(lds + 1024);
        int*   ri     = (int*)  (lds + 1088);
        int*   winner = (int*)  (lds + 1152);
        for (int f = 0; f < nf; ++f) {
            int rowl = flist[f];
            if (t < DIM) zsh[t] = x[(r0 + rowl) * DIM + t];
            __syncthreads();
            float zn = 0.f;
            #pragma unroll
            for (int d = 0; d < DIM; ++d) zn = __builtin_fmaf(zsh[d], zsh[d], zn);
            float a0 = 0.f, a1 = 0.f, a2 = 0.f, a3 = 0.f;
            #pragma unroll
            for (int d = 0; d < DIM; ++d) {
                float zd = zsh[d];
                const float* Ed = E + d * K_CODES;
                a0 = __builtin_fmaf(zd, Ed[t      ], a0);
                a1 = __builtin_fmaf(zd, Ed[t + 256], a1);
                a2 = __builtin_fmaf(zd, Ed[t + 512], a2);
                a3 = __builtin_fmaf(zd, Ed[t + 768], a3);
            }
            float d0 = __builtin_fmaf(-2.f, a0, zn + nrm[t      ]);
            float d1 = __builtin_fmaf(-2.f, a1, zn + nrm[t + 256]);
            float d2 = __builtin_fmaf(-2.f, a2, zn + nrm[t + 512]);
            float d3 = __builtin_fmaf(-2.f, a3, zn + nrm[t + 768]);
            float bv = d0; int bi = t;                       // ascending, strict <
            if (d1 < bv) { bv = d1; bi = t + 256; }
            if (d2 < bv) { bv = d2; bi = t + 512; }
            if (d3 < bv) { bv = d3; bi = t + 768; }
            #pragma unroll
            for (int m = 1; m < 64; m <<= 1) {
                float ov = __shfl_xor(bv, m, 64);
                int   oi = __shfl_xor(bi, m, 64);
                if (ov < bv || (ov == bv && oi < bi)) { bv = ov; bi = oi; }
            }
            if (lane == 0) { rv[wv] = bv; ri[wv] = bi; }
            __syncthreads();
            if (t == 0) {
                float v = rv[0]; int b = ri[0];
                #pragma unroll
                for (int w = 1; w < 4; ++w)
                    if (rv[w] < v || (rv[w] == v && ri[w] < b)) { v = rv[w]; b = ri[w]; }
                *winner = b;
            }
            __syncthreads();
            if (t < DIM) out[(r0 + rowl) * DIM + t] = Et[(size_t)(*winner) * DIM + t];
            __syncthreads();
        }
    }
}

extern "C" void kernel_launch(void* const* d_in, const int* in_sizes, int n_in,
                              void* d_out, int out_size, void* d_ws, size_t ws_size,
                              hipStream_t stream) {
    const float* x = (const float*)d_in[0];
    const float* E = (const float*)d_in[1];
    float* out = (float*)d_out;

    char* ws = (char*)d_ws;
    float*          Et   = (float*)ws;                        // 256 KiB
    unsigned short* Eh   = (unsigned short*)(ws + 262144);    // 128 KiB
    unsigned short* El   = (unsigned short*)(ws + 393216);    // 128 KiB
    float*          nrm  = (float*)(ws + 524288);             // 4 KiB
    float*          nrm2 = (float*)(ws + 528384);             // 4 KiB

    int nrows = in_sizes[0] / DIM;                            // 65536

    vq_prep2<<<64, 256, 0, stream>>>(E, Et, Eh, El, nrm, nrm2);
    vq_mfma<<<nrows / BR, 256, 0, stream>>>(x, E, Eh, El, nrm, nrm2, Et, out);
}

// Round 9
// 123.506 us; speedup vs baseline: 1.5998x; 1.5998x over previous
//
#include <hip/hip_runtime.h>
#include <float.h>

#define K_CODES 1024
#define DIM 64
#define BR 128
// Distances in the MFMA path are HALF-scale (ne/2 - sim, z pre-negated,
// norms pre-halved). bf16x3 half-scale error bound: 3*2^-18*||z||*||e||
// <= 7e-5 worst-case; gate at 1.25e-4 (== round-5/6's 2.5e-4 full-scale,
// which flagged ~113/65536 rows).
#define SAFE_MARGIN_H 1.25e-4f

typedef __attribute__((ext_vector_type(8))) short bf16x8;
typedef __attribute__((ext_vector_type(8))) unsigned short u16x8;
typedef __attribute__((ext_vector_type(4))) float f32x4;

__device__ __forceinline__ unsigned short f2bf(float f) {
    unsigned int u = __float_as_uint(f);
    u += 0x7fff + ((u >> 16) & 1);          // round-to-nearest-even
    return (unsigned short)(u >> 16);
}
__device__ __forceinline__ float bf2f(unsigned short h) {
    return __uint_as_float(((unsigned int)h) << 16);
}
// XOR swizzle for 128-byte LDS rows, applied on BOTH write & read sides.
__device__ __forceinline__ int swz(int row, int byteInRow) {
    return row * 128 + (byteInRow ^ ((row & 7) << 4));
}

// ---------- prep: transpose E, bf16 hi/lo splits, norms (+halved) ----------
__global__ __launch_bounds__(256) void vq_prep2(
    const float* __restrict__ E, float* __restrict__ Et,
    unsigned short* __restrict__ Eh, unsigned short* __restrict__ El,
    float* __restrict__ nrm, float* __restrict__ nrm2)
{
    __shared__ float T[64 * 17];
    const int t = threadIdx.x;
    const int k0 = blockIdx.x * 16;
    #pragma unroll
    for (int i = 0; i < 4; ++i) {
        int idx = i * 256 + t;
        int d = idx >> 4, kk = idx & 15;
        T[d * 17 + kk] = E[d * K_CODES + k0 + kk];
    }
    __syncthreads();
    #pragma unroll
    for (int i = 0; i < 4; ++i) {
        int idx = i * 256 + t;
        int kk = idx >> 6, d = idx & 63;
        float v = T[d * 17 + kk];
        Et[(size_t)(k0 + kk) * DIM + d] = v;
        unsigned short h = f2bf(v);
        Eh[(size_t)(k0 + kk) * DIM + d] = h;
        El[(size_t)(k0 + kk) * DIM + d] = f2bf(v - bf2f(h));
    }
    if (t < 16) {
        float s = 0.f;
        #pragma unroll
        for (int d = 0; d < DIM; ++d) {
            float v = T[d * 17 + t];
            s = __builtin_fmaf(v, v, s);
        }
        nrm [k0 + t] = s;
        nrm2[k0 + t] = 0.5f * s;    // exact (exponent decrement)
    }
}

// ---------- main: bf16x3 MFMA + med3 top-2 + fused gather + fused refine ----------
// LDS overlay: [0,32K) = A-stage (Ah|Al), then reused per-chunk as B (Bh|Bl),
// then reused by the (rare) refine phase. [32K,...) = bidx / flag list / fcnt.
// launch_bounds kept at (256,2): round 7 showed (256,4) caps the unified
// VGPR/AGPR budget at 128 and spills the main loop (+18 MB scratch writes).
__global__ __launch_bounds__(256, 2) void vq_mfma(
    const float* __restrict__ x,
    const float* __restrict__ E,
    const unsigned short* __restrict__ Eh,
    const unsigned short* __restrict__ El,
    const float* __restrict__ nrm,
    const float* __restrict__ nrm2,
    const float* __restrict__ Et,
    float* __restrict__ out)
{
    __shared__ char lds[32768 + 512 + 512 + 16];
    char* Ah = lds;                      // 16 KB (stage phase)
    char* Al = lds + 16384;              // 16 KB (stage phase)
    char* Bh = lds;                      // 16 KB (chunk phase)
    char* Bl = lds + 16384;              // 16 KB (chunk phase)
    int*  bidx  = (int*)(lds + 32768);   // 128 winners
    int*  flist = (int*)(lds + 33280);   // flagged local rows (<=128)
    int*  fcnt  = (int*)(lds + 33792);

    const int t    = threadIdx.x;
    const int lane = t & 63;
    const int wv   = t >> 6;
    const int col  = lane & 15;
    const int q    = lane >> 4;
    const int koff = q * 16;
    const long r0  = (long)blockIdx.x * BR;

    if (t == 0) *fcnt = 0;

    // ---- stage A: load x rows, split NEGATED fp32 -> bf16 hi/lo ----
    {
        int row = t >> 1, h = t & 1;
        const float4* src = (const float4*)(x + (r0 + row) * DIM + h * 32);
        float v[32];
        #pragma unroll
        for (int i = 0; i < 8; ++i) {
            float4 f = src[i];
            v[4*i+0] = -f.x; v[4*i+1] = -f.y; v[4*i+2] = -f.z; v[4*i+3] = -f.w;
        }
        unsigned short hi[32], lo[32];
        #pragma unroll
        for (int i = 0; i < 32; ++i) {
            hi[i] = f2bf(v[i]);
            lo[i] = f2bf(v[i] - bf2f(hi[i]));
        }
        #pragma unroll
        for (int s = 0; s < 2; ++s) {
            int seg = h * 2 + s;
            *(u16x8*)(Ah + swz(row, seg*32))      = *(u16x8*)(hi + s*16);
            *(u16x8*)(Ah + swz(row, seg*32 + 16)) = *(u16x8*)(hi + s*16 + 8);
            *(u16x8*)(Al + swz(row, seg*32))      = *(u16x8*)(lo + s*16);
            *(u16x8*)(Al + swz(row, seg*32 + 16)) = *(u16x8*)(lo + s*16 + 8);
        }
    }
    __syncthreads();

    // ---- A fragments (-z) held in VGPRs: A[row=lane&15][k=(lane>>4)*8+j] ----
    bf16x8 aH[2][2], aL[2][2];
    #pragma unroll
    for (int m = 0; m < 2; ++m) {
        int arow = wv * 32 + m * 16 + col;
        #pragma unroll
        for (int kk = 0; kk < 2; ++kk) {
            aH[m][kk] = *(bf16x8*)(Ah + swz(arow, kk*64 + koff));
            aL[m][kk] = *(bf16x8*)(Al + swz(arow, kk*64 + koff));
        }
    }
    __syncthreads();   // frags read; A region may be overwritten by B chunks

    float b1[2][4], b2[2][4];
    int   i1[2][4];
    #pragma unroll
    for (int m = 0; m < 2; ++m)
        #pragma unroll
        for (int j = 0; j < 4; ++j) { b1[m][j] = FLT_MAX; b2[m][j] = FLT_MAX; i1[m][j] = 0x7fffffff; }

    for (int c0 = 0; c0 < K_CODES; c0 += 128) {
        // stage B chunk into the (now free) 32 KB region
        #pragma unroll
        for (int i = 0; i < 4; ++i) {
            int idx = i * 256 + t;
            int cr = idx >> 3, sg = idx & 7;
            *(u16x8*)(Bh + swz(cr, sg*16)) = *(const u16x8*)(Eh + (size_t)(c0+cr)*DIM + sg*8);
            *(u16x8*)(Bl + swz(cr, sg*16)) = *(const u16x8*)(El + (size_t)(c0+cr)*DIM + sg*8);
        }
        __syncthreads();

        #pragma unroll
        for (int nt = 0; nt < 8; ++nt) {
            int brow = nt * 16 + col;
            bf16x8 bH0 = *(bf16x8*)(Bh + swz(brow, koff));
            bf16x8 bH1 = *(bf16x8*)(Bh + swz(brow, 64 + koff));
            bf16x8 bL0 = *(bf16x8*)(Bl + swz(brow, koff));
            bf16x8 bL1 = *(bf16x8*)(Bl + swz(brow, 64 + koff));
            int code = c0 + nt * 16 + col;
            float ne2 = nrm2[code];
            #pragma unroll
            for (int m = 0; m < 2; ++m) {
                f32x4 acc = {ne2, ne2, ne2, ne2};   // C-in carries ne/2; A = -z
                acc = __builtin_amdgcn_mfma_f32_16x16x32_bf16(aH[m][0], bH0, acc, 0,0,0);
                acc = __builtin_amdgcn_mfma_f32_16x16x32_bf16(aH[m][1], bH1, acc, 0,0,0);
                acc = __builtin_amdgcn_mfma_f32_16x16x32_bf16(aH[m][0], bL0, acc, 0,0,0);
                acc = __builtin_amdgcn_mfma_f32_16x16x32_bf16(aH[m][1], bL1, acc, 0,0,0);
                acc = __builtin_amdgcn_mfma_f32_16x16x32_bf16(aL[m][0], bH0, acc, 0,0,0);
                acc = __builtin_amdgcn_mfma_f32_16x16x32_bf16(aL[m][1], bH1, acc, 0,0,0);
                #pragma unroll
                for (int j = 0; j < 4; ++j) {
                    float d = acc[j];               // = ne/2 - sim' directly
                    bool lt = d < b1[m][j];
                    float nb1 = fminf(b1[m][j], d);
                    b2[m][j] = __builtin_amdgcn_fmed3f(b1[m][j], b2[m][j], d);
                    i1[m][j] = lt ? code : i1[m][j];
                    b1[m][j] = nb1;
                }
            }
        }
        __syncthreads();   // compute done; next chunk may overwrite B
    }

    // ---- top-2 merge across the 16 lanes holding each row ----
    #pragma unroll
    for (int msk = 1; msk < 16; msk <<= 1) {
        #pragma unroll
        for (int m = 0; m < 2; ++m)
            #pragma unroll
            for (int j = 0; j < 4; ++j) {
                float o1 = __shfl_xor(b1[m][j], msk, 64);
                int   oi = __shfl_xor(i1[m][j], msk, 64);
                float o2 = __shfl_xor(b2[m][j], msk, 64);
                bool take = (o1 < b1[m][j]) || (o1 == b1[m][j] && oi < i1[m][j]);
                float worst = take ? b1[m][j] : o1;
                if (take) { b1[m][j] = o1; i1[m][j] = oi; }
                b2[m][j] = fminf(fminf(b2[m][j], o2), worst);
            }
    }
    if (col == 0) {
        #pragma unroll
        for (int m = 0; m < 2; ++m)
            #pragma unroll
            for (int j = 0; j < 4; ++j) {
                int rowl = wv * 32 + m * 16 + q * 4 + j;   // C/D: row=(lane>>4)*4+reg
                bidx[rowl] = i1[m][j];
                if (b2[m][j] - b1[m][j] <= SAFE_MARGIN_H) {
                    int p = atomicAdd(fcnt, 1);            // LDS atomic
                    flist[p] = rowl;
                }
            }
    }
    __syncthreads();

    // ---- fused gather: bit-exact embedding rows ----
    {
        int rowl = t >> 1, h = t & 1;
        int code = bidx[rowl];
        const float4* src = (const float4*)(Et + (size_t)code * DIM + h * 32);
        float4* dst = (float4*)(out + (size_t)(r0 + rowl) * DIM + h * 32);
        #pragma unroll
        for (int i = 0; i < 8; ++i) dst[i] = src[i];
    }
    __syncthreads();

    // ---- fused refine: exact fp32 re-solve for flagged rows (rare) ----
    // Proven arithmetic: sequential-d fmaf chains, fmaf(-2, acc, zn + nrm).
    // 4 codes/thread (t, t+256, t+512, t+768), coalesced native-E reads.
    const int nf = *fcnt;
    if (nf > 0) {
        float* zsh    = (float*)lds;            // B region is free now
        float* rv     = (float*)(lds + 1024);
        int*   ri     = (int*)  (lds + 1088);
        int*   winner = (int*)  (lds + 1152);
        for (int f = 0; f < nf; ++f) {
            int rowl = flist[f];
            if (t < DIM) zsh[t] = x[(r0 + rowl) * DIM + t];
            __syncthreads();
            float zn = 0.f;
            #pragma unroll
            for (int d = 0; d < DIM; ++d) zn = __builtin_fmaf(zsh[d], zsh[d], zn);
            float a0 = 0.f, a1 = 0.f, a2 = 0.f, a3 = 0.f;
            #pragma unroll
            for (int d = 0; d < DIM; ++d) {
                float zd = zsh[d];
                const float* Ed = E + d * K_CODES;
                a0 = __builtin_fmaf(zd, Ed[t      ], a0);
                a1 = __builtin_fmaf(zd, Ed[t + 256], a1);
                a2 = __builtin_fmaf(zd, Ed[t + 512], a2);
                a3 = __builtin_fmaf(zd, Ed[t + 768], a3);
            }
            float d0 = __builtin_fmaf(-2.f, a0, zn + nrm[t      ]);
            float d1 = __builtin_fmaf(-2.f, a1, zn + nrm[t + 256]);
            float d2 = __builtin_fmaf(-2.f, a2, zn + nrm[t + 512]);
            float d3 = __builtin_fmaf(-2.f, a3, zn + nrm[t + 768]);
            float bv = d0; int bi = t;                       // ascending, strict <
            if (d1 < bv) { bv = d1; bi = t + 256; }
            if (d2 < bv) { bv = d2; bi = t + 512; }
            if (d3 < bv) { bv = d3; bi = t + 768; }
            #pragma unroll
            for (int m = 1; m < 64; m <<= 1) {
                float ov = __shfl_xor(bv, m, 64);
                int   oi = __shfl_xor(bi, m, 64);
                if (ov < bv || (ov == bv && oi < bi)) { bv = ov; bi = oi; }
            }
            if (lane == 0) { rv[wv] = bv; ri[wv] = bi; }
            __syncthreads();
            if (t == 0) {
                float v = rv[0]; int b = ri[0];
                #pragma unroll
                for (int w = 1; w < 4; ++w)
                    if (rv[w] < v || (rv[w] == v && ri[w] < b)) { v = rv[w]; b = ri[w]; }
                *winner = b;
            }
            __syncthreads();
            if (t < DIM) out[(r0 + rowl) * DIM + t] = Et[(size_t)(*winner) * DIM + t];
            __syncthreads();
        }
    }
}

extern "C" void kernel_launch(void* const* d_in, const int* in_sizes, int n_in,
                              void* d_out, int out_size, void* d_ws, size_t ws_size,
                              hipStream_t stream) {
    const float* x = (const float*)d_in[0];
    const float* E = (const float*)d_in[1];
    float* out = (float*)d_out;

    char* ws = (char*)d_ws;
    float*          Et   = (float*)ws;                        // 256 KiB
    unsigned short* Eh   = (unsigned short*)(ws + 262144);    // 128 KiB
    unsigned short* El   = (unsigned short*)(ws + 393216);    // 128 KiB
    float*          nrm  = (float*)(ws + 524288);             // 4 KiB
    float*          nrm2 = (float*)(ws + 528384);             // 4 KiB

    int nrows = in_sizes[0] / DIM;                            // 65536

    vq_prep2<<<64, 256, 0, stream>>>(E, Et, Eh, El, nrm, nrm2);
    vq_mfma<<<nrows / BR, 256, 0, stream>>>(x, E, Eh, El, nrm, nrm2, Et, out);
}

// Round 11
// 121.537 us; speedup vs baseline: 1.6257x; 1.0162x over previous
//
#include <hip/hip_runtime.h>
#include <float.h>

#define K_CODES 1024
#define DIM 64
#define BR 64
// Half-scale distances (ne/2 - sim, z pre-negated, norms pre-halved).
// bf16x3 half-scale error bound <= 7e-5 worst-case; gate 1.25e-4
// (== 2.5e-4 full-scale, measured ~113/65536 flagged rows in round 5).
#define SAFE_MARGIN_H 1.25e-4f

typedef __attribute__((ext_vector_type(8))) short bf16x8;
typedef __attribute__((ext_vector_type(8))) unsigned short u16x8;
typedef __attribute__((ext_vector_type(4))) float f32x4;

__device__ __forceinline__ unsigned short f2bf(float f) {
    unsigned int u = __float_as_uint(f);
    u += 0x7fff + ((u >> 16) & 1);          // round-to-nearest-even
    return (unsigned short)(u >> 16);
}
__device__ __forceinline__ float bf2f(unsigned short h) {
    return __uint_as_float(((unsigned int)h) << 16);
}
// XOR swizzle for 128-byte LDS rows, applied on BOTH write & read sides.
__device__ __forceinline__ int swz(int row, int byteInRow) {
    return row * 128 + (byteInRow ^ ((row & 7) << 4));
}

// ---------- prep: transpose E, bf16 hi/lo splits, norms, zero counter ----------
__global__ __launch_bounds__(256) void vq_prep2(
    const float* __restrict__ E, float* __restrict__ Et,
    unsigned short* __restrict__ Eh, unsigned short* __restrict__ El,
    float* __restrict__ nrm, float* __restrict__ nrm2, int* __restrict__ cnt)
{
    __shared__ float T[64 * 17];
    const int t = threadIdx.x;
    const int k0 = blockIdx.x * 16;
    if (blockIdx.x == 0 && t == 0) *cnt = 0;
    #pragma unroll
    for (int i = 0; i < 4; ++i) {
        int idx = i * 256 + t;
        int d = idx >> 4, kk = idx & 15;
        T[d * 17 + kk] = E[d * K_CODES + k0 + kk];
    }
    __syncthreads();
    #pragma unroll
    for (int i = 0; i < 4; ++i) {
        int idx = i * 256 + t;
        int kk = idx >> 6, d = idx & 63;
        float v = T[d * 17 + kk];
        Et[(size_t)(k0 + kk) * DIM + d] = v;
        unsigned short h = f2bf(v);
        Eh[(size_t)(k0 + kk) * DIM + d] = h;
        El[(size_t)(k0 + kk) * DIM + d] = f2bf(v - bf2f(h));
    }
    if (t < 16) {
        float s = 0.f;
        #pragma unroll
        for (int d = 0; d < DIM; ++d) {
            float v = T[d * 17 + t];
            s = __builtin_fmaf(v, v, s);
        }
        nrm [k0 + t] = s;
        nrm2[k0 + t] = 0.5f * s;    // exact (exponent decrement)
    }
}

// ---------- main: 64-row blocks (1024 blocks = 4/CU), bf16x3 MFMA ----------
// LDS 32.3 KB: A-stage [0,16K) overlaid by per-chunk B [0,32K); bidx after.
// No fused refine (round 9: its liveness pushed VGPR to the 128 bucket and
// spilled 3 MB); flags go to a global list consumed by vq_refine3.
__global__ __launch_bounds__(256, 2) void vq_mfma(
    const float* __restrict__ x,
    const unsigned short* __restrict__ Eh,
    const unsigned short* __restrict__ El,
    const float* __restrict__ nrm2,
    const float* __restrict__ Et,
    float* __restrict__ out,
    int* __restrict__ cnt, int* __restrict__ list)
{
    __shared__ char lds[32768 + 256];
    char* Ah = lds;                      // 8 KB (stage phase)
    char* Al = lds + 8192;               // 8 KB (stage phase)
    char* Bh = lds;                      // 16 KB (chunk phase)
    char* Bl = lds + 16384;              // 16 KB (chunk phase)
    int*  bidx = (int*)(lds + 32768);    // 64 winners

    const int t    = threadIdx.x;
    const int lane = t & 63;
    const int wv   = t >> 6;
    const int col  = lane & 15;
    const int q    = lane >> 4;
    const int koff = q * 16;
    const long r0  = (long)blockIdx.x * BR;

    // ---- stage A: 64 rows; thread = (row = t>>2, quarter = t&3) ----
    {
        int row = t >> 2, qh = t & 3;
        const float4* src = (const float4*)(x + (r0 + row) * DIM + qh * 16);
        float v[16];
        #pragma unroll
        for (int i = 0; i < 4; ++i) {
            float4 f = src[i];
            v[4*i+0] = -f.x; v[4*i+1] = -f.y; v[4*i+2] = -f.z; v[4*i+3] = -f.w;
        }
        unsigned short hi[16], lo[16];
        #pragma unroll
        for (int i = 0; i < 16; ++i) {
            hi[i] = f2bf(v[i]);
            lo[i] = f2bf(v[i] - bf2f(hi[i]));
        }
        *(u16x8*)(Ah + swz(row, qh*32))      = *(u16x8*)(hi);
        *(u16x8*)(Ah + swz(row, qh*32 + 16)) = *(u16x8*)(hi + 8);
        *(u16x8*)(Al + swz(row, qh*32))      = *(u16x8*)(lo);
        *(u16x8*)(Al + swz(row, qh*32 + 16)) = *(u16x8*)(lo + 8);
    }
    __syncthreads();

    // ---- A fragments (-z): A[row=lane&15][k=(lane>>4)*8+j], 16 rows/wave ----
    bf16x8 aH[2], aL[2];
    {
        int arow = wv * 16 + col;
        #pragma unroll
        for (int kk = 0; kk < 2; ++kk) {
            aH[kk] = *(bf16x8*)(Ah + swz(arow, kk*64 + koff));
            aL[kk] = *(bf16x8*)(Al + swz(arow, kk*64 + koff));
        }
    }
    __syncthreads();   // frags in regs; A region now reusable for B chunks

    float b1[4], b2[4];
    int   i1[4];
    #pragma unroll
    for (int j = 0; j < 4; ++j) { b1[j] = FLT_MAX; b2[j] = FLT_MAX; i1[j] = 0x7fffffff; }

    for (int c0 = 0; c0 < K_CODES; c0 += 128) {
        // stage B chunk: 128 codes x 64 dims, hi+lo
        #pragma unroll
        for (int i = 0; i < 4; ++i) {
            int idx = i * 256 + t;
            int cr = idx >> 3, sg = idx & 7;
            *(u16x8*)(Bh + swz(cr, sg*16)) = *(const u16x8*)(Eh + (size_t)(c0+cr)*DIM + sg*8);
            *(u16x8*)(Bl + swz(cr, sg*16)) = *(const u16x8*)(El + (size_t)(c0+cr)*DIM + sg*8);
        }
        __syncthreads();

        #pragma unroll
        for (int nt = 0; nt < 8; ++nt) {
            int brow = nt * 16 + col;
            bf16x8 bH0 = *(bf16x8*)(Bh + swz(brow, koff));
            bf16x8 bH1 = *(bf16x8*)(Bh + swz(brow, 64 + koff));
            bf16x8 bL0 = *(bf16x8*)(Bl + swz(brow, koff));
            bf16x8 bL1 = *(bf16x8*)(Bl + swz(brow, 64 + koff));
            int code = c0 + nt * 16 + col;
            float ne2 = nrm2[code];
            f32x4 acc = {ne2, ne2, ne2, ne2};   // C-in carries ne/2; A = -z
            acc = __builtin_amdgcn_mfma_f32_16x16x32_bf16(aH[0], bH0, acc, 0,0,0);
            acc = __builtin_amdgcn_mfma_f32_16x16x32_bf16(aH[1], bH1, acc, 0,0,0);
            acc = __builtin_amdgcn_mfma_f32_16x16x32_bf16(aH[0], bL0, acc, 0,0,0);
            acc = __builtin_amdgcn_mfma_f32_16x16x32_bf16(aH[1], bL1, acc, 0,0,0);
            acc = __builtin_amdgcn_mfma_f32_16x16x32_bf16(aL[0], bH0, acc, 0,0,0);
            acc = __builtin_amdgcn_mfma_f32_16x16x32_bf16(aL[1], bH1, acc, 0,0,0);
            #pragma unroll
            for (int j = 0; j < 4; ++j) {
                float d = acc[j];               // = ne/2 - sim' directly
                bool lt = d < b1[j];
                float nb1 = fminf(b1[j], d);
                b2[j] = __builtin_amdgcn_fmed3f(b1[j], b2[j], d);
                i1[j] = lt ? code : i1[j];
                b1[j] = nb1;
            }
        }
        __syncthreads();   // compute done; next chunk may overwrite B
    }

    // ---- top-2 merge across the 16 lanes holding each row ----
    #pragma unroll
    for (int msk = 1; msk < 16; msk <<= 1) {
        #pragma unroll
        for (int j = 0; j < 4; ++j) {
            float o1 = __shfl_xor(b1[j], msk, 64);
            int   oi = __shfl_xor(i1[j], msk, 64);
            float o2 = __shfl_xor(b2[j], msk, 64);
            bool take = (o1 < b1[j]) || (o1 == b1[j] && oi < i1[j]);
            float worst = take ? b1[j] : o1;
            if (take) { b1[j] = o1; i1[j] = oi; }
            b2[j] = fminf(fminf(b2[j], o2), worst);
        }
    }
    if (col == 0) {
        #pragma unroll
        for (int j = 0; j < 4; ++j) {
            int rowl = wv * 16 + q * 4 + j;     // C/D: row=(lane>>4)*4+reg
            bidx[rowl] = i1[j];
            if (b2[j] - b1[j] <= SAFE_MARGIN_H) {
                int p = atomicAdd(cnt, 1);      // global, rare (~100 total)
                list[p] = (int)(r0 + rowl);
            }
        }
    }
    __syncthreads();

    // ---- fused gather: bit-exact embedding rows ----
    {
        int row = t >> 2, qh = t & 3;
        int code = bidx[row];
        const float4* src = (const float4*)(Et + (size_t)code * DIM + qh * 16);
        float4* dst = (float4*)(out + (size_t)(r0 + row) * DIM + qh * 16);
        #pragma unroll
        for (int i = 0; i < 4; ++i) dst[i] = src[i];
    }
}

// ---------- refine: exact fp32 re-solve, one BLOCK per flagged row ----------
// Proven arithmetic (absmax 0.0 in rounds 6/7/9): sequential-d fmaf chains,
// fmaf(-2, acc, zn + nrm); 4 codes/thread, coalesced native-E reads.
__global__ __launch_bounds__(256) void vq_refine3(
    const float* __restrict__ x, const float* __restrict__ E,
    const float* __restrict__ Et, const float* __restrict__ nrm,
    float* __restrict__ out,
    const int* __restrict__ cnt, const int* __restrict__ list)
{
    __shared__ float zsh[DIM];
    __shared__ float rv[4];
    __shared__ int   ri[4];
    __shared__ int   winner;
    const int n = *cnt;
    const int t = threadIdx.x;
    const int lane = t & 63, wv = t >> 6;

    for (int i = blockIdx.x; i < n; i += gridDim.x) {
        int row = list[i];
        if (t < DIM) zsh[t] = x[(size_t)row * DIM + t];
        __syncthreads();
        float zn = 0.f;
        #pragma unroll
        for (int d = 0; d < DIM; ++d) zn = __builtin_fmaf(zsh[d], zsh[d], zn);
        float a0 = 0.f, a1 = 0.f, a2 = 0.f, a3 = 0.f;
        #pragma unroll
        for (int d = 0; d < DIM; ++d) {
            float zd = zsh[d];
            const float* Ed = E + d * K_CODES;
            a0 = __builtin_fmaf(zd, Ed[t      ], a0);
            a1 = __builtin_fmaf(zd, Ed[t + 256], a1);
            a2 = __builtin_fmaf(zd, Ed[t + 512], a2);
            a3 = __builtin_fmaf(zd, Ed[t + 768], a3);
        }
        float d0 = __builtin_fmaf(-2.f, a0, zn + nrm[t      ]);
        float d1 = __builtin_fmaf(-2.f, a1, zn + nrm[t + 256]);
        float d2 = __builtin_fmaf(-2.f, a2, zn + nrm[t + 512]);
        float d3 = __builtin_fmaf(-2.f, a3, zn + nrm[t + 768]);
        float bv = d0; int bi = t;                       // ascending, strict <
        if (d1 < bv) { bv = d1; bi = t + 256; }
        if (d2 < bv) { bv = d2; bi = t + 512; }
        if (d3 < bv) { bv = d3; bi = t + 768; }
        #pragma unroll
        for (int m = 1; m < 64; m <<= 1) {
            float ov = __shfl_xor(bv, m, 64);
            int   oi = __shfl_xor(bi, m, 64);
            if (ov < bv || (ov == bv && oi < bi)) { bv = ov; bi = oi; }
        }
        if (lane == 0) { rv[wv] = bv; ri[wv] = bi; }
        __syncthreads();
        if (t == 0) {
            float v = rv[0]; int b = ri[0];
            #pragma unroll
            for (int w = 1; w < 4; ++w)
                if (rv[w] < v || (rv[w] == v && ri[w] < b)) { v = rv[w]; b = ri[w]; }
            winner = b;
        }
        __syncthreads();
        if (t < DIM) out[(size_t)row * DIM + t] = Et[(size_t)winner * DIM + t];
        __syncthreads();                                 // before zsh reuse
    }
}

extern "C" void kernel_launch(void* const* d_in, const int* in_sizes, int n_in,
                              void* d_out, int out_size, void* d_ws, size_t ws_size,
                              hipStream_t stream) {
    const float* x = (const float*)d_in[0];
    const float* E = (const float*)d_in[1];
    float* out = (float*)d_out;

    char* ws = (char*)d_ws;
    float*          Et   = (float*)ws;                        // 256 KiB
    unsigned short* Eh   = (unsigned short*)(ws + 262144);    // 128 KiB
    unsigned short* El   = (unsigned short*)(ws + 393216);    // 128 KiB
    float*          nrm  = (float*)(ws + 524288);             // 4 KiB
    float*          nrm2 = (float*)(ws + 528384);             // 4 KiB
    int*            cnt  = (int*)(ws + 532480);               // 4 B
    int*            list = (int*)(ws + 532736);               // 256 KiB

    int nrows = in_sizes[0] / DIM;                            // 65536

    vq_prep2<<<64, 256, 0, stream>>>(E, Et, Eh, El, nrm, nrm2, cnt);
    vq_mfma<<<nrows / BR, 256, 0, stream>>>(x, Eh, El, nrm2, Et, out, cnt, list);
    vq_refine3<<<512, 256, 0, stream>>>(x, E, Et, nrm, out, cnt, list);
}